// Round 3
// baseline (233.808 us; speedup 1.0000x reference)
//
#include <hip/hip_runtime.h>
#include <math.h>

#define NTOK 1024
#define QDIM 512
#define NH 8
#define DHD 64

using s16x8 = __attribute__((ext_vector_type(8))) short;
using f32x4 = __attribute__((ext_vector_type(4))) float;

__device__ __forceinline__ unsigned short f2bf(float x) {
  union { float f; unsigned u; } v; v.f = x;
  unsigned r = (v.u + 0x7fffu + ((v.u >> 16) & 1u)) >> 16;
  return (unsigned short)r;
}
__device__ __forceinline__ float bf2f(unsigned short h) {
  union { unsigned u; float f; } v; v.u = ((unsigned)h) << 16;
  return v.f;
}
__device__ __forceinline__ unsigned cvt_pk_bf16(float lo, float hi) {
  unsigned r;
  asm volatile("v_cvt_pk_bf16_f32 %0, %1, %2" : "=v"(r) : "v"(lo), "v"(hi));
  return r;
}

// ---------------- cast x + weights to bf16 (contiguous dst) ----------------
__global__ __launch_bounds__(256) void cast_kernel(
    const float* __restrict__ x, const float* __restrict__ Wq, const float* __restrict__ Wk,
    const float* __restrict__ Wv, const float* __restrict__ Wo, unsigned short* __restrict__ dst)
{
  const int tid = blockIdx.x * 256 + threadIdx.x;   // 524288 threads
  const int e = tid * 4;
  const float* src;
  if (e < 1048576) {
    src = x + e;
  } else {
    const int we = e - 1048576;
    const int wi = we >> 18;          // 0..3
    const int off = we & 262143;
    src = (wi == 0 ? Wq : wi == 1 ? Wk : wi == 2 ? Wv : Wo) + off;
  }
  float4 v = *(const float4*)src;
  ushort4 o;
  o.x = f2bf(v.x); o.y = f2bf(v.y); o.z = f2bf(v.z); o.w = f2bf(v.w);
  *(ushort4*)&dst[e] = o;
}

// ---------------- QKV projection (MFMA): q pre-scaled; V written transposed ----------------
__global__ __launch_bounds__(256) void proj_mfma_kernel(
    const unsigned short* __restrict__ x_b, const unsigned short* __restrict__ w_b,
    unsigned short* __restrict__ q_b, unsigned short* __restrict__ k_b,
    unsigned short* __restrict__ v_bT)
{
  const int w = threadIdx.x >> 6;
  const int l = threadIdx.x & 63;
  const int lq = l & 15, lg = l >> 4;
  const int tile = blockIdx.x * 4 + w;          // 0..127 (16-token tiles)
  const int mat = blockIdx.y >> 3;              // 0:q 1:k 2:v
  const int h = blockIdx.y & 7;
  const unsigned short* W = w_b + (size_t)mat * 262144 + (size_t)(h * 64) * QDIM;
  const int tok0 = tile * 16;

  __shared__ unsigned short T[4][64][24];       // only used by mat==2

  f32x4 acc[4] = {};
  for (int kt = 0; kt < 16; ++kt) {
    s16x8 a = *(const s16x8*)&x_b[(size_t)(tok0 + lq) * QDIM + kt * 32 + lg * 8];
#pragma unroll
    for (int nf = 0; nf < 4; ++nf) {
      s16x8 bfr = *(const s16x8*)&W[(size_t)(nf * 16 + lq) * QDIM + kt * 32 + lg * 8];
      acc[nf] = __builtin_amdgcn_mfma_f32_16x16x32_bf16(a, bfr, acc[nf], 0, 0, 0);
    }
  }

  const int b = tok0 >> 10;
  const int tl0 = tok0 & 1023;
  if (mat < 2) {
    const float scale = (mat == 0) ? 0.125f : 1.0f;
    unsigned short* dp = (mat == 0 ? q_b : k_b) + (size_t)(b * NH + h) * NTOK * DHD;
#pragma unroll
    for (int nf = 0; nf < 4; ++nf)
#pragma unroll
      for (int r = 0; r < 4; ++r)
        dp[(size_t)(tl0 + lg * 4 + r) * DHD + nf * 16 + lq] = f2bf(acc[nf][r] * scale);
  } else {
    // transpose 16tok x 64d -> 64d x 16tok via LDS, then 32B rows out
#pragma unroll
    for (int nf = 0; nf < 4; ++nf)
#pragma unroll
      for (int r = 0; r < 4; ++r)
        T[w][nf * 16 + lq][lg * 4 + r] = f2bf(acc[nf][r]);
    // wave-synchronous: same-wave ds_write -> ds_read is ordered
    unsigned short* dp = v_bT + (size_t)(b * NH + h) * NTOK * DHD + (size_t)l * NTOK + tl0;
    *(uint4*)&dp[0] = *(const uint4*)&T[w][l][0];
    *(uint4*)&dp[8] = *(const uint4*)&T[w][l][8];
  }
}

// ---------------- AdaIN (stats + apply, one kernel; k row-major, v transposed) ----------------
__global__ __launch_bounds__(512) void adain_kernel(
    unsigned short* __restrict__ k_b, unsigned short* __restrict__ v_bT,
    const float* __restrict__ mask)
{
  const int arr = blockIdx.x >> 3;   // 0:k 1:v
  const int h = blockIdx.x & 7;
  const int t = threadIdx.x;

  __shared__ float mlds[1024];
  __shared__ float red[4][512];
  __shared__ float sA[64], sB[64];
  __shared__ float scnt;

  {
    int i0 = t;
    mlds[i0] = mask[(i0 >> 5) * 128 + (i0 & 31) * 2];
    int i1 = t + 512;
    mlds[i1] = mask[(i1 >> 5) * 128 + (i1 & 31) * 2];
  }
  __syncthreads();
  if (t < 64) {
    float c = 0.f;
    for (int i = t; i < 1024; i += 64) c += mlds[i];
#pragma unroll
    for (int off = 1; off < 64; off <<= 1) c += __shfl_xor(c, off);
    if (t == 0) scnt = c;
  }
  __syncthreads();
  const float cnt = scnt;

  if (arr == 0) {
    unsigned short* refp = k_b + (size_t)h * 65536;
    unsigned short* fep  = k_b + (size_t)(8 + h) * 65536;
    const int dh = t & 63, ig = t >> 6;
    float rs = 0.f, rq = 0.f, fs = 0.f, fq = 0.f;
    for (int i = ig; i < 1024; i += 8) {
      const float rv = bf2f(refp[i * 64 + dh]);
      rs += rv; rq += rv * rv;
      const float fv = bf2f(fep[i * 64 + dh]);
      const float mm = mlds[i];
      fs += mm * fv; fq += mm * fv * fv;
    }
    red[0][t] = rs; red[1][t] = rq; red[2][t] = fs; red[3][t] = fq;
    __syncthreads();
    if (ig == 0) {
      rs = 0.f; rq = 0.f; fs = 0.f; fq = 0.f;
#pragma unroll
      for (int g = 0; g < 8; ++g) {
        rs += red[0][g * 64 + dh]; rq += red[1][g * 64 + dh];
        fs += red[2][g * 64 + dh]; fq += red[3][g * 64 + dh];
      }
      const float rmean = rs * (1.0f / 1024.0f);
      const float rstd = sqrtf(fmaxf((rq - 1024.0f * rmean * rmean) * (1.0f / 1023.0f), 0.f));
      const float fmean = fs / cnt;
      const float fstd = sqrtf(fmaxf((fq - cnt * fmean * fmean) / (cnt - 1.0f), 0.f));
      const float a = rstd / fstd;
      sA[dh] = a; sB[dh] = rmean - fmean * a;
    }
    __syncthreads();
    const float a = sA[dh], bb = sB[dh];
    for (int i = ig; i < 1024; i += 8)
      if (mlds[i] != 0.f)
        fep[i * 64 + dh] = f2bf(bf2f(fep[i * 64 + dh]) * a + bb);
  } else {
    unsigned short* refp = v_bT + (size_t)h * 65536;
    unsigned short* fep  = v_bT + (size_t)(8 + h) * 65536;
    const int d = t >> 3, seg = t & 7;
    const int i0 = seg * 128;
    float rs = 0.f, rq = 0.f, fs = 0.f, fq = 0.f;
    for (int ii = 0; ii < 16; ++ii) {
      s16x8 rv8 = *(const s16x8*)&refp[d * 1024 + i0 + ii * 8];
      s16x8 fv8 = *(const s16x8*)&fep[d * 1024 + i0 + ii * 8];
#pragma unroll
      for (int j = 0; j < 8; ++j) {
        const float rv = bf2f((unsigned short)rv8[j]);
        rs += rv; rq += rv * rv;
        const float fv = bf2f((unsigned short)fv8[j]);
        const float mm = mlds[i0 + ii * 8 + j];
        fs += mm * fv; fq += mm * fv * fv;
      }
    }
#pragma unroll
    for (int off = 1; off < 8; off <<= 1) {
      rs += __shfl_xor(rs, off); rq += __shfl_xor(rq, off);
      fs += __shfl_xor(fs, off); fq += __shfl_xor(fq, off);
    }
    const float rmean = rs * (1.0f / 1024.0f);
    const float rstd = sqrtf(fmaxf((rq - 1024.0f * rmean * rmean) * (1.0f / 1023.0f), 0.f));
    const float fmean = fs / cnt;
    const float fstd = sqrtf(fmaxf((fq - cnt * fmean * fmean) / (cnt - 1.0f), 0.f));
    const float a = rstd / fstd;
    const float bb = rmean - fmean * a;
    for (int ii = 0; ii < 16; ++ii) {
      s16x8 fv8 = *(const s16x8*)&fep[d * 1024 + i0 + ii * 8];
#pragma unroll
      for (int j = 0; j < 8; ++j) {
        if (mlds[i0 + ii * 8 + j] != 0.f) {
          const float fv = bf2f((unsigned short)fv8[j]);
          fv8[j] = (short)f2bf(fv * a + bb);
        }
      }
      *(s16x8*)&fep[d * 1024 + i0 + ii * 8] = fv8;
    }
  }
}

// ---------------- flash attention: 2 waves/block, LDS-staged KV, defer-max ----------------
__global__ __launch_bounds__(128) void attn_mfma_kernel(
    const unsigned short* __restrict__ q_b, const unsigned short* __restrict__ k_b,
    const unsigned short* __restrict__ v_bT, const float* __restrict__ mask,
    unsigned short* __restrict__ o_b)
{
  const int bh = blockIdx.y, b = bh >> 3, h = bh & 7;
  const int w = threadIdx.x >> 6;
  const int q0 = blockIdx.x * 32 + w * 16;
  const int l = threadIdx.x & 63, lq = l & 15, lg = l >> 4;
  const int tid = threadIdx.x;

  __shared__ unsigned short Kbuf[2][4096];
  __shared__ unsigned short Vbuf[2][4096];
  __shared__ unsigned int P_u[2][16][36];

  const unsigned short* qrow = q_b + ((size_t)bh * NTOK + q0 + lq) * DHD + lg * 8;
  s16x8 qf0 = *(const s16x8*)&qrow[0];
  s16x8 qf1 = *(const s16x8*)&qrow[32];

  const int qt = q0 + lq;
  const float mneg = (b == 1) ? (1.0f - mask[(qt >> 5) * 128 + (qt & 31) * 2]) * (-1e9f) : 0.0f;

  const int NT = (b == 0) ? 16 : 32;   // batch 0: KV halves are identical -> softmax equal
  const size_t own = (size_t)bh * 65536, ref = (size_t)h * 65536;

  float mrow = -1e30f, lrow = 0.f;
  f32x4 oacc[4] = {};
  uint4 kreg[4], vreg[4];

#define ATT_LOADS(T_)                                                          \
  {                                                                            \
    const size_t base_ = ((T_) < 16) ? own : ref;                              \
    const unsigned short* kb_ = k_b + base_ + (size_t)(((T_) & 15) * 64) * DHD;\
    const unsigned short* vb_ = v_bT + base_ + ((T_) & 15) * 64;               \
    _Pragma("unroll")                                                          \
    for (int i_ = 0; i_ < 4; ++i_) {                                           \
      const int ci_ = i_ * 128 + tid;                                          \
      const int row_ = ci_ >> 3, cc_ = ci_ & 7;                                \
      kreg[i_] = *(const uint4*)(kb_ + (size_t)row_ * DHD + cc_ * 8);          \
      vreg[i_] = *(const uint4*)(vb_ + (size_t)row_ * NTOK + cc_ * 8);         \
    }                                                                          \
  }

#define ATT_WRITE(BUF_)                                                        \
  {                                                                            \
    _Pragma("unroll")                                                          \
    for (int i_ = 0; i_ < 4; ++i_) {                                           \
      const int ci_ = i_ * 128 + tid;                                          \
      const int row_ = ci_ >> 3, cc_ = ci_ & 7;                                \
      const int sw_ = (cc_ ^ (row_ & 7)) << 4;                                 \
      *(uint4*)((char*)Kbuf[BUF_] + row_ * 128 + sw_) = kreg[i_];              \
      *(uint4*)((char*)Vbuf[BUF_] + row_ * 128 + sw_) = vreg[i_];              \
    }                                                                          \
  }

  ATT_LOADS(0);
  ATT_WRITE(0);
  __syncthreads();

  int cur = 0;
  for (int t = 0; t < NT; ++t) {
    if (t + 1 < NT) ATT_LOADS(t + 1);

    // ---- QK^T:  S^T[kv][q] ----
    const char* Kb = (const char*)Kbuf[cur];
    f32x4 sf[4];
#pragma unroll
    for (int mf = 0; mf < 4; ++mf) {
      const int r = mf * 16 + lq;
      s16x8 a0 = *(const s16x8*)(Kb + r * 128 + ((lg ^ (r & 7)) << 4));
      s16x8 a1 = *(const s16x8*)(Kb + r * 128 + (((lg + 4) ^ (r & 7)) << 4));
      f32x4 z = {};
      z = __builtin_amdgcn_mfma_f32_16x16x32_bf16(a0, qf0, z, 0, 0, 0);
      sf[mf] = __builtin_amdgcn_mfma_f32_16x16x32_bf16(a1, qf1, z, 0, 0, 0);
    }
    const float add = (t >= 16) ? mneg : 0.0f;
    float tm = -1e30f;
#pragma unroll
    for (int mf = 0; mf < 4; ++mf)
#pragma unroll
      for (int r = 0; r < 4; ++r) { sf[mf][r] += add; tm = fmaxf(tm, sf[mf][r]); }
    tm = fmaxf(tm, __shfl_xor(tm, 16));
    tm = fmaxf(tm, __shfl_xor(tm, 32));

    // defer-max: only rescale when the running max grows materially
    if (!__all(tm <= mrow + 8.0f)) {
      const float mnew = fmaxf(mrow, tm);
      const float alpha = __expf(mrow - mnew);
      mrow = mnew;
      lrow *= alpha;
      float ar[4];
#pragma unroll
      for (int r = 0; r < 4; ++r) ar[r] = __shfl(alpha, lg * 4 + r, 16);
#pragma unroll
      for (int nf = 0; nf < 4; ++nf)
#pragma unroll
        for (int r = 0; r < 4; ++r) oacc[nf][r] *= ar[r];
    }

    float p[4][4];
    float ps = 0.f;
#pragma unroll
    for (int mf = 0; mf < 4; ++mf)
#pragma unroll
      for (int r = 0; r < 4; ++r) { const float e = __expf(sf[mf][r] - mrow); p[mf][r] = e; ps += e; }
    ps += __shfl_xor(ps, 16);
    ps += __shfl_xor(ps, 32);
    lrow += ps;

#pragma unroll
    for (int mf = 0; mf < 4; ++mf) {
      uint2 wv;
      wv.x = cvt_pk_bf16(p[mf][0], p[mf][1]);
      wv.y = cvt_pk_bf16(p[mf][2], p[mf][3]);
      *(uint2*)&P_u[w][lq][8 * mf + 2 * lg] = wv;
    }

    // ---- O += P * V ----
    const char* Vb = (const char*)Vbuf[cur];
#pragma unroll
    for (int ks = 0; ks < 2; ++ks) {
      s16x8 pa = *(const s16x8*)&P_u[w][lq][16 * ks + 4 * lg];
#pragma unroll
      for (int nf = 0; nf < 4; ++nf) {
        const int rv = nf * 16 + lq;
        s16x8 vb = *(const s16x8*)(Vb + rv * 128 + ((((ks << 2) + lg) ^ (rv & 7)) << 4));
        oacc[nf] = __builtin_amdgcn_mfma_f32_16x16x32_bf16(pa, vb, oacc[nf], 0, 0, 0);
      }
    }

    if (t + 1 < NT) ATT_WRITE(cur ^ 1);
    __syncthreads();
    cur ^= 1;
  }

  float rinv[4];
#pragma unroll
  for (int r = 0; r < 4; ++r) rinv[r] = 1.0f / __shfl(lrow, lg * 4 + r, 16);
  unsigned short* op = o_b + ((size_t)bh * NTOK + q0) * DHD;
#pragma unroll
  for (int nf = 0; nf < 4; ++nf)
#pragma unroll
    for (int r = 0; r < 4; ++r)
      op[(size_t)(lg * 4 + r) * DHD + nf * 16 + lq] = f2bf(oacc[nf][r] * rinv[r]);
#undef ATT_LOADS
#undef ATT_WRITE
}

// ---------------- output projection (MFMA) + bias, fp32 out ----------------
__global__ __launch_bounds__(256) void outproj_mfma_kernel(
    const unsigned short* __restrict__ o_b, const unsigned short* __restrict__ Wo_b,
    const float* __restrict__ bo, float* __restrict__ out)
{
  const int w = threadIdx.x >> 6, l = threadIdx.x & 63;
  const int lq = l & 15, lg = l >> 4;
  const int tile = blockIdx.x * 4 + w;          // 0..127
  const int c0 = blockIdx.y * 64;
  const int tok = tile * 16 + lq;
  const int b = tok >> 10, tl = tok & 1023;

  f32x4 acc[4] = {};
  for (int kt = 0; kt < 16; ++kt) {
    const int k0 = kt * 32 + lg * 8;
    const int hh = k0 >> 6, dd = k0 & 63;
    s16x8 a = *(const s16x8*)&o_b[((size_t)(b * NH + hh) * NTOK + tl) * DHD + dd];
#pragma unroll
    for (int nf = 0; nf < 4; ++nf) {
      s16x8 bfr = *(const s16x8*)&Wo_b[(size_t)(c0 + nf * 16 + lq) * QDIM + k0];
      acc[nf] = __builtin_amdgcn_mfma_f32_16x16x32_bf16(a, bfr, acc[nf], 0, 0, 0);
    }
  }
  const int row0 = tile * 16;
#pragma unroll
  for (int nf = 0; nf < 4; ++nf) {
    const float bv = bo[c0 + nf * 16 + lq];
#pragma unroll
    for (int r = 0; r < 4; ++r)
      out[(size_t)(row0 + lg * 4 + r) * QDIM + c0 + nf * 16 + lq] = acc[nf][r] + bv;
  }
}

extern "C" void kernel_launch(void* const* d_in, const int* in_sizes, int n_in,
                              void* d_out, int out_size, void* d_ws, size_t ws_size,
                              hipStream_t stream) {
  const float* x    = (const float*)d_in[0];
  const float* mask = (const float*)d_in[1];
  const float* Wq   = (const float*)d_in[2];
  const float* Wk   = (const float*)d_in[3];
  const float* Wv   = (const float*)d_in[4];
  const float* Wo   = (const float*)d_in[5];
  const float* bo   = (const float*)d_in[6];
  float* out = (float*)d_out;

  char* ws = (char*)d_ws;
  unsigned short* x_b  = (unsigned short*)ws;                    // 2 MB
  unsigned short* w_b  = (unsigned short*)(ws + 2097152);        // Wq,Wk,Wv,Wo: 2 MB
  unsigned short* Wo_b = (unsigned short*)(ws + 2097152 + 3 * 524288);
  unsigned short* q_b  = (unsigned short*)(ws + 4194304);
  unsigned short* k_b  = (unsigned short*)(ws + 6291456);
  unsigned short* v_bT = (unsigned short*)(ws + 8388608);
  unsigned short* o_b  = (unsigned short*)(ws + 10485760);

  cast_kernel<<<2048, 256, 0, stream>>>(x, Wq, Wk, Wv, Wo, x_b);
  proj_mfma_kernel<<<dim3(32, 24), 256, 0, stream>>>(x_b, w_b, q_b, k_b, v_bT);
  adain_kernel<<<16, 512, 0, stream>>>(k_b, v_bT, mask);
  attn_mfma_kernel<<<dim3(32, 16), 128, 0, stream>>>(q_b, k_b, v_bT, mask, o_b);
  outproj_mfma_kernel<<<dim3(32, 8), 256, 0, stream>>>(o_b, Wo_b, bo, out);
}

// Round 4
// 176.794 us; speedup vs baseline: 1.3225x; 1.3225x over previous
//
#include <hip/hip_runtime.h>
#include <math.h>

#define NTOK 1024
#define QDIM 512
#define NH 8
#define DHD 64

using s16x8 = __attribute__((ext_vector_type(8))) short;
using f32x4 = __attribute__((ext_vector_type(4))) float;

__device__ __forceinline__ unsigned short f2bf(float x) {
  union { float f; unsigned u; } v; v.f = x;
  unsigned r = (v.u + 0x7fffu + ((v.u >> 16) & 1u)) >> 16;
  return (unsigned short)r;
}
__device__ __forceinline__ float bf2f(unsigned short h) {
  union { unsigned u; float f; } v; v.u = ((unsigned)h) << 16;
  return v.f;
}
__device__ __forceinline__ unsigned cvt_pk_bf16(float lo, float hi) {
  unsigned r;
  asm volatile("v_cvt_pk_bf16_f32 %0, %1, %2" : "=v"(r) : "v"(lo), "v"(hi));
  return r;
}

// ---------------- cast x + weights to bf16 ----------------
__global__ __launch_bounds__(256) void cast_kernel(
    const float* __restrict__ x, const float* __restrict__ Wq, const float* __restrict__ Wk,
    const float* __restrict__ Wv, const float* __restrict__ Wo, unsigned short* __restrict__ dst)
{
  const int tid = blockIdx.x * 256 + threadIdx.x;
  const int e = tid * 4;
  const float* src;
  if (e < 1048576) {
    src = x + e;
  } else {
    const int we = e - 1048576;
    const int wi = we >> 18;
    const int off = we & 262143;
    src = (wi == 0 ? Wq : wi == 1 ? Wk : wi == 2 ? Wv : Wo) + off;
  }
  float4 v = *(const float4*)src;
  ushort4 o;
  o.x = f2bf(v.x); o.y = f2bf(v.y); o.z = f2bf(v.z); o.w = f2bf(v.w);
  *(ushort4*)&dst[e] = o;
}

// ---------------- QKV projection (MFMA): q pre-scaled, all row-major ----------------
__global__ __launch_bounds__(256) void proj_mfma_kernel(
    const unsigned short* __restrict__ x_b, const unsigned short* __restrict__ w_b,
    unsigned short* __restrict__ q_b, unsigned short* __restrict__ k_b,
    unsigned short* __restrict__ v_b)
{
  const int w = threadIdx.x >> 6;
  const int l = threadIdx.x & 63;
  const int lq = l & 15, lg = l >> 4;
  const int tile = blockIdx.x * 4 + w;
  const int mat = blockIdx.y >> 3;
  const int h = blockIdx.y & 7;
  const unsigned short* W = w_b + (size_t)mat * 262144 + (size_t)(h * 64) * QDIM;
  const int tok0 = tile * 16;

  f32x4 acc[4] = {};
  for (int kt = 0; kt < 16; ++kt) {
    s16x8 a = *(const s16x8*)&x_b[(size_t)(tok0 + lq) * QDIM + kt * 32 + lg * 8];
#pragma unroll
    for (int nf = 0; nf < 4; ++nf) {
      s16x8 bfr = *(const s16x8*)&W[(size_t)(nf * 16 + lq) * QDIM + kt * 32 + lg * 8];
      acc[nf] = __builtin_amdgcn_mfma_f32_16x16x32_bf16(a, bfr, acc[nf], 0, 0, 0);
    }
  }

  const float scale = (mat == 0) ? 0.125f : 1.0f;
  unsigned short* dst = (mat == 0 ? q_b : mat == 1 ? k_b : v_b);
  const int b = tok0 >> 10;
  const int tl0 = tok0 & 1023;
  unsigned short* dp = dst + (size_t)(b * NH + h) * NTOK * DHD;
#pragma unroll
  for (int nf = 0; nf < 4; ++nf)
#pragma unroll
    for (int r = 0; r < 4; ++r)
      dp[(size_t)(tl0 + lg * 4 + r) * DHD + nf * 16 + lq] = f2bf(acc[nf][r] * scale);
}

// ---------------- AdaIN stats: per-chunk partials, no atomics ----------------
__global__ __launch_bounds__(256) void adain_stats_kernel(
    const unsigned short* __restrict__ k_b, const unsigned short* __restrict__ v_b,
    const float* __restrict__ mask, float* __restrict__ stats_p, float* __restrict__ stats_cnt)
{
  const int id = blockIdx.x;              // 256 = arr(2) x h(8) x ch(16)
  const int arr = id >> 7, h = (id >> 4) & 7, ch = id & 15;
  const unsigned short* base = arr ? v_b : k_b;
  const unsigned short* refp = base + (size_t)h * 65536;
  const unsigned short* fep  = base + (size_t)(8 + h) * 65536;
  const int t = threadIdx.x, dh = t & 63, ig = t >> 6;

  if (arr == 0 && h == 0 && t < 64) {
    const int tok = ch * 64 + t;
    float c = mask[(tok >> 5) * 128 + (tok & 31) * 2];
#pragma unroll
    for (int off = 1; off < 64; off <<= 1) c += __shfl_xor(c, off);
    if (t == 0) stats_cnt[ch] = c;
  }

  float rs = 0.f, rq = 0.f, fs = 0.f, fq = 0.f;
  for (int i = 0; i < 16; ++i) {
    const int tok = ch * 64 + ig * 16 + i;
    const float rv = bf2f(refp[(size_t)tok * DHD + dh]);
    rs += rv; rq += rv * rv;
    const float fv = bf2f(fep[(size_t)tok * DHD + dh]);
    const float mm = mask[(tok >> 5) * 128 + (tok & 31) * 2];
    fs += mm * fv; fq += mm * fv * fv;
  }
  __shared__ float red[4][256];
  red[0][t] = rs; red[1][t] = rq; red[2][t] = fs; red[3][t] = fq;
  __syncthreads();
  if (ig == 0) {
    rs = red[0][dh] + red[0][dh + 64] + red[0][dh + 128] + red[0][dh + 192];
    rq = red[1][dh] + red[1][dh + 64] + red[1][dh + 128] + red[1][dh + 192];
    fs = red[2][dh] + red[2][dh + 64] + red[2][dh + 128] + red[2][dh + 192];
    fq = red[3][dh] + red[3][dh + 64] + red[3][dh + 128] + red[3][dh + 192];
    float* sp = stats_p + (size_t)id * 256;
    sp[dh] = rs; sp[64 + dh] = rq; sp[128 + dh] = fs; sp[192 + dh] = fq;
  }
}

// ---------------- AdaIN apply: reduce partials inline, then transform ----------------
__global__ __launch_bounds__(256) void adain_apply_kernel(
    unsigned short* __restrict__ k_b, unsigned short* __restrict__ v_b,
    const float* __restrict__ mask, const float* __restrict__ stats_p,
    const float* __restrict__ stats_cnt)
{
  const int id = blockIdx.x;
  const int arr = id >> 7, h = (id >> 4) & 7, ch = id & 15;
  unsigned short* fep = (arr ? v_b : k_b) + (size_t)(8 + h) * 65536;
  const int t = threadIdx.x, dh = t & 63, ig = t >> 6;

  __shared__ float sA[64], sB[64];
  if (t < 64) {
    float cnt = 0.f;
#pragma unroll
    for (int c = 0; c < 16; ++c) cnt += stats_cnt[c];
    const float* sp = stats_p + (size_t)((arr << 7) | (h << 4)) * 256;
    float rs = 0.f, rq = 0.f, fs = 0.f, fq = 0.f;
#pragma unroll
    for (int c = 0; c < 16; ++c) {
      rs += sp[c * 256 + t]; rq += sp[c * 256 + 64 + t];
      fs += sp[c * 256 + 128 + t]; fq += sp[c * 256 + 192 + t];
    }
    const float rmean = rs * (1.0f / 1024.0f);
    const float rstd = sqrtf(fmaxf((rq - 1024.0f * rmean * rmean) * (1.0f / 1023.0f), 0.f));
    const float fmean = fs / cnt;
    const float fstd = sqrtf(fmaxf((fq - cnt * fmean * fmean) / (cnt - 1.0f), 0.f));
    const float a = rstd / fstd;
    sA[t] = a; sB[t] = rmean - fmean * a;
  }
  __syncthreads();
  const float a = sA[dh], bb = sB[dh];
  for (int i = 0; i < 16; ++i) {
    const int tok = ch * 64 + ig * 16 + i;
    if (mask[(tok >> 5) * 128 + (tok & 31) * 2] != 0.f) {
      const float fv = bf2f(fep[(size_t)tok * DHD + dh]);
      fep[(size_t)tok * DHD + dh] = f2bf(fv * a + bb);
    }
  }
}

// ---------------- V transpose (post-AdaIN): v_b [bh][tok][dh] -> v_bT [bh][dh][tok] ----------------
__global__ __launch_bounds__(256) void vtrans_kernel(const unsigned short* __restrict__ v_b,
                                                     unsigned short* __restrict__ v_bT)
{
  const int bh = blockIdx.y;
  const int tc = blockIdx.x;
  __shared__ unsigned short T[64][72];
  const int t = threadIdx.x;
  {
    const int tok = t >> 2, d0 = (t & 3) * 16;
    const unsigned short* src = v_b + ((size_t)bh * NTOK + tc * 64 + tok) * DHD + d0;
    ushort4 a0 = *(const ushort4*)&src[0];
    ushort4 a1 = *(const ushort4*)&src[4];
    ushort4 a2 = *(const ushort4*)&src[8];
    ushort4 a3 = *(const ushort4*)&src[12];
    T[d0 + 0][tok] = a0.x; T[d0 + 1][tok] = a0.y; T[d0 + 2][tok] = a0.z; T[d0 + 3][tok] = a0.w;
    T[d0 + 4][tok] = a1.x; T[d0 + 5][tok] = a1.y; T[d0 + 6][tok] = a1.z; T[d0 + 7][tok] = a1.w;
    T[d0 + 8][tok] = a2.x; T[d0 + 9][tok] = a2.y; T[d0 +10][tok] = a2.z; T[d0 +11][tok] = a2.w;
    T[d0 +12][tok] = a3.x; T[d0 +13][tok] = a3.y; T[d0 +14][tok] = a3.z; T[d0 +15][tok] = a3.w;
  }
  __syncthreads();
  {
    const int dh = t >> 2, t0 = (t & 3) * 16;
    unsigned short* dst = v_bT + ((size_t)bh * DHD + dh) * NTOK + tc * 64 + t0;
    s16x8 r0 = *(const s16x8*)&T[dh][t0];
    s16x8 r1 = *(const s16x8*)&T[dh][t0 + 8];
    *(s16x8*)&dst[0] = r0;
    *(s16x8*)&dst[8] = r1;
  }
}

// ---------------- attention partial: 1 wave per (bh, qtile, kv-slot) ----------------
__global__ __launch_bounds__(64) void attn_part_kernel(
    const unsigned short* __restrict__ q_b, const unsigned short* __restrict__ k_b,
    const unsigned short* __restrict__ v_bT, const float* __restrict__ mask,
    unsigned short* __restrict__ pO, float* __restrict__ pml)
{
  const int id = blockIdx.x;              // 4096 = bh(16) x qt(64) x s(4)
  const int bh = id >> 8, b = bh >> 3, h = bh & 7;
  const int qt = (id >> 2) & 63, s = id & 3;
  const int q0 = qt * 16;
  const int l = threadIdx.x, lq = l & 15, lg = l >> 4;

  __shared__ unsigned int P_u[16][36];

  const unsigned short* qrow = q_b + ((size_t)bh * NTOK + q0 + lq) * DHD + lg * 8;
  s16x8 qf0 = *(const s16x8*)&qrow[0];
  s16x8 qf1 = *(const s16x8*)&qrow[32];

  const int qtok = q0 + lq;
  const float mneg = (b == 1) ? (1.0f - mask[(qtok >> 5) * 128 + (qtok & 31) * 2]) * (-1e9f) : 0.0f;

  const size_t own = (size_t)bh * 65536, ref = (size_t)h * 65536;
  const int ntile = (b == 0) ? 4 : 8;     // b0: 4x64=256 kv; b1: 8x64=512 kv
  const int kv0 = s * ((b == 0) ? 256 : 512);

  float mrow = -1e30f, lrow = 0.f;
  f32x4 oacc[4] = {};

  for (int tt = 0; tt < ntile; ++tt) {
    const int kvtok = kv0 + tt * 64;
    const int inref = (kvtok >= NTOK) ? 1 : 0;
    const size_t base = inref ? ref : own;
    const int off = inref ? (kvtok - NTOK) : kvtok;
    const unsigned short* kp = k_b + base + (size_t)off * DHD;
    const unsigned short* vp = v_bT + base + off;

    // S^T = K . Q^T
    f32x4 sf[4];
#pragma unroll
    for (int mf = 0; mf < 4; ++mf) {
      s16x8 a0 = *(const s16x8*)&kp[(size_t)(mf * 16 + lq) * DHD + lg * 8];
      s16x8 a1 = *(const s16x8*)&kp[(size_t)(mf * 16 + lq) * DHD + 32 + lg * 8];
      f32x4 z = {};
      z = __builtin_amdgcn_mfma_f32_16x16x32_bf16(a0, qf0, z, 0, 0, 0);
      sf[mf] = __builtin_amdgcn_mfma_f32_16x16x32_bf16(a1, qf1, z, 0, 0, 0);
    }

    const float add = inref ? mneg : 0.0f;
    float tm = -1e30f;
#pragma unroll
    for (int mf = 0; mf < 4; ++mf)
#pragma unroll
      for (int r = 0; r < 4; ++r) { sf[mf][r] += add; tm = fmaxf(tm, sf[mf][r]); }
    tm = fmaxf(tm, __shfl_xor(tm, 16));
    tm = fmaxf(tm, __shfl_xor(tm, 32));

    if (!__all(tm <= mrow + 8.0f)) {
      const float mnew = fmaxf(mrow, tm);
      const float alpha = __expf(mrow - mnew);
      mrow = mnew;
      lrow *= alpha;
      float ar[4];
#pragma unroll
      for (int r = 0; r < 4; ++r) ar[r] = __shfl(alpha, lg * 4 + r, 16);
#pragma unroll
      for (int nf = 0; nf < 4; ++nf)
#pragma unroll
        for (int r = 0; r < 4; ++r) oacc[nf][r] *= ar[r];
    }

    float p[4][4];
    float ps = 0.f;
#pragma unroll
    for (int mf = 0; mf < 4; ++mf)
#pragma unroll
      for (int r = 0; r < 4; ++r) { const float e = __expf(sf[mf][r] - mrow); p[mf][r] = e; ps += e; }
    ps += __shfl_xor(ps, 16);
    ps += __shfl_xor(ps, 32);
    lrow += ps;

#pragma unroll
    for (int mf = 0; mf < 4; ++mf) {
      uint2 wv;
      wv.x = cvt_pk_bf16(p[mf][0], p[mf][1]);
      wv.y = cvt_pk_bf16(p[mf][2], p[mf][3]);
      *(uint2*)&P_u[lq][8 * mf + 2 * lg] = wv;
    }

    // O += P . V
#pragma unroll
    for (int ks = 0; ks < 2; ++ks) {
      s16x8 pa = *(const s16x8*)&P_u[lq][16 * ks + 4 * lg];
#pragma unroll
      for (int nf = 0; nf < 4; ++nf) {
        s16x8 vb = *(const s16x8*)&vp[(size_t)(nf * 16 + lq) * NTOK + ks * 32 + lg * 8];
        oacc[nf] = __builtin_amdgcn_mfma_f32_16x16x32_bf16(pa, vb, oacc[nf], 0, 0, 0);
      }
    }
  }

  const int u = (bh * 64 + qt) * 4 + s;
  unsigned short* pop = pO + (size_t)u * 1024;
#pragma unroll
  for (int nf = 0; nf < 4; ++nf)
#pragma unroll
    for (int r = 0; r < 4; ++r)
      pop[(size_t)(lg * 4 + r) * DHD + nf * 16 + lq] = f2bf(oacc[nf][r]);
  if (l < 16) {
    pml[(size_t)u * 32 + lq] = mrow;
    pml[(size_t)u * 32 + 16 + lq] = lrow;
  }
}

// ---------------- attention merge: combine 4 partials per (bh, qtile) ----------------
__global__ __launch_bounds__(64) void attn_merge_kernel(
    const unsigned short* __restrict__ pO, const float* __restrict__ pml,
    unsigned short* __restrict__ o_b)
{
  const int id = blockIdx.x;              // 1024 = bh(16) x qt(64)
  const int bh = id >> 6, qt = id & 63;
  const int l = threadIdx.x, r = l & 15, dblk = l >> 4;
  const int d0 = dblk * 16;
  const int base_u = (bh * 64 + qt) * 4;

  float ms[4], ls[4];
  float M = -1e30f;
#pragma unroll
  for (int s = 0; s < 4; ++s) {
    ms[s] = pml[(size_t)(base_u + s) * 32 + r];
    ls[s] = pml[(size_t)(base_u + s) * 32 + 16 + r];
    M = fmaxf(M, ms[s]);
  }
  float Lsum = 0.f;
  float o[16];
#pragma unroll
  for (int j = 0; j < 16; ++j) o[j] = 0.f;
#pragma unroll
  for (int s = 0; s < 4; ++s) {
    const float alpha = __expf(ms[s] - M);
    Lsum += alpha * ls[s];
    const unsigned short* po = pO + (size_t)(base_u + s) * 1024 + (size_t)r * DHD + d0;
    s16x8 a = *(const s16x8*)&po[0];
    s16x8 c = *(const s16x8*)&po[8];
#pragma unroll
    for (int j = 0; j < 8; ++j) {
      o[j] += alpha * bf2f((unsigned short)a[j]);
      o[8 + j] += alpha * bf2f((unsigned short)c[j]);
    }
  }
  const float inv = 1.0f / Lsum;
  unsigned short* dst = o_b + ((size_t)bh * NTOK + qt * 16 + r) * DHD + d0;
  ushort4 w0, w1, w2, w3;
  w0.x = f2bf(o[0] * inv);  w0.y = f2bf(o[1] * inv);  w0.z = f2bf(o[2] * inv);  w0.w = f2bf(o[3] * inv);
  w1.x = f2bf(o[4] * inv);  w1.y = f2bf(o[5] * inv);  w1.z = f2bf(o[6] * inv);  w1.w = f2bf(o[7] * inv);
  w2.x = f2bf(o[8] * inv);  w2.y = f2bf(o[9] * inv);  w2.z = f2bf(o[10] * inv); w2.w = f2bf(o[11] * inv);
  w3.x = f2bf(o[12] * inv); w3.y = f2bf(o[13] * inv); w3.z = f2bf(o[14] * inv); w3.w = f2bf(o[15] * inv);
  *(ushort4*)&dst[0] = w0; *(ushort4*)&dst[4] = w1;
  *(ushort4*)&dst[8] = w2; *(ushort4*)&dst[12] = w3;
}

// ---------------- output projection (MFMA) + bias, fp32 out ----------------
__global__ __launch_bounds__(256) void outproj_mfma_kernel(
    const unsigned short* __restrict__ o_b, const unsigned short* __restrict__ Wo_b,
    const float* __restrict__ bo, float* __restrict__ out)
{
  const int w = threadIdx.x >> 6, l = threadIdx.x & 63;
  const int lq = l & 15, lg = l >> 4;
  const int tile = blockIdx.x * 4 + w;
  const int c0 = blockIdx.y * 64;
  const int tok = tile * 16 + lq;
  const int b = tok >> 10, tl = tok & 1023;

  f32x4 acc[4] = {};
  for (int kt = 0; kt < 16; ++kt) {
    const int k0 = kt * 32 + lg * 8;
    const int hh = k0 >> 6, dd = k0 & 63;
    s16x8 a = *(const s16x8*)&o_b[((size_t)(b * NH + hh) * NTOK + tl) * DHD + dd];
#pragma unroll
    for (int nf = 0; nf < 4; ++nf) {
      s16x8 bfr = *(const s16x8*)&Wo_b[(size_t)(c0 + nf * 16 + lq) * QDIM + k0];
      acc[nf] = __builtin_amdgcn_mfma_f32_16x16x32_bf16(a, bfr, acc[nf], 0, 0, 0);
    }
  }
  const int row0 = tile * 16;
#pragma unroll
  for (int nf = 0; nf < 4; ++nf) {
    const float bv = bo[c0 + nf * 16 + lq];
#pragma unroll
    for (int r = 0; r < 4; ++r)
      out[(size_t)(row0 + lg * 4 + r) * QDIM + c0 + nf * 16 + lq] = acc[nf][r] + bv;
  }
}

extern "C" void kernel_launch(void* const* d_in, const int* in_sizes, int n_in,
                              void* d_out, int out_size, void* d_ws, size_t ws_size,
                              hipStream_t stream) {
  const float* x    = (const float*)d_in[0];
  const float* mask = (const float*)d_in[1];
  const float* Wq   = (const float*)d_in[2];
  const float* Wk   = (const float*)d_in[3];
  const float* Wv   = (const float*)d_in[4];
  const float* Wo   = (const float*)d_in[5];
  const float* bo   = (const float*)d_in[6];
  float* out = (float*)d_out;

  char* ws = (char*)d_ws;
  unsigned short* x_b  = (unsigned short*)ws;                          // 2 MB
  unsigned short* w_b  = (unsigned short*)(ws + 2097152);              // 2 MB (Wq,Wk,Wv,Wo)
  unsigned short* Wo_b = (unsigned short*)(ws + 2097152 + 3 * 524288);
  unsigned short* q_b  = (unsigned short*)(ws + 4194304);              // 2 MB
  unsigned short* k_b  = (unsigned short*)(ws + 6291456);              // 2 MB
  unsigned short* v_b  = (unsigned short*)(ws + 8388608);              // 2 MB
  unsigned short* v_bT = (unsigned short*)(ws + 10485760);             // 2 MB
  unsigned short* o_b  = (unsigned short*)(ws + 12582912);             // 2 MB
  unsigned short* pO   = (unsigned short*)(ws + 14680064);             // 8 MB (4096 x 1024 bf16)
  float* pml      = (float*)(ws + 23068672);                           // 512 KB
  float* stats_p  = (float*)(ws + 23592960);                           // 256 KB
  float* stats_cnt = (float*)(ws + 23855104);                          // 64 B

  cast_kernel<<<2048, 256, 0, stream>>>(x, Wq, Wk, Wv, Wo, x_b);
  proj_mfma_kernel<<<dim3(32, 24), 256, 0, stream>>>(x_b, w_b, q_b, k_b, v_b);
  adain_stats_kernel<<<256, 256, 0, stream>>>(k_b, v_b, mask, stats_p, stats_cnt);
  adain_apply_kernel<<<256, 256, 0, stream>>>(k_b, v_b, mask, stats_p, stats_cnt);
  vtrans_kernel<<<dim3(16, 16), 256, 0, stream>>>(v_b, v_bT);
  attn_part_kernel<<<4096, 64, 0, stream>>>(q_b, k_b, v_bT, mask, pO, pml);
  attn_merge_kernel<<<1024, 64, 0, stream>>>(pO, pml, o_b);
  outproj_mfma_kernel<<<dim3(32, 8), 256, 0, stream>>>(o_b, Wo_b, bo, out);
}